// Round 3
// baseline (54.298 us; speedup 1.0000x reference)
//
#include <hip/hip_runtime.h>

// x[n] = 0.95 * x[n-1] + e[n], 64 rows x 480000 fp32, row-major.
// Single-pass block-local scan: each block handles an 8192-element tile of one
// row. Incoming state is approximated by a geometric-weighted reduction over
// the preceding 512 elements (0.95^512 ~ 4e-12 -> exact for fp32 purposes).
// 8 elements/thread, nontemporal output stores (output is never re-read;
// keeps the input resident in L3 so warm-up reads don't go to HBM).

#define ROW_N   480000
#define TILE    8192
#define WARM    512
#define NTILES  ((ROW_N + TILE - 1) / TILE)   // 59
#define NROWS   64

typedef float vfloat4 __attribute__((ext_vector_type(4)));  // clang-native for nontemporal builtin

__global__ __launch_bounds__(1024)
void deemph_kernel(const float* __restrict__ in, float* __restrict__ out) {
    const int row      = blockIdx.y;
    const int startcol = blockIdx.x * TILE;
    const int tid      = threadIdx.x;
    const int lane     = tid & 63;
    const int wave     = tid >> 6;

    const float* __restrict__ rin  = in  + (size_t)row * ROW_N;
    float*       __restrict__ rout = out + (size_t)row * ROW_N;

    __shared__ float warr[16];   // per-wave inclusive scan carries
    __shared__ float wsum[16];   // per-wave warm-up partial sums

    const float LOG2C = -0.07400058144377693f;  // log2(0.95)

    // ---- warm-up: carry_warm ~= x[startcol-1] = sum_j c^(511-j) e[start-512+j]
    // threads 0..127 each load one float4 of the 512-elem window.
    float wpart = 0.0f;
    if (startcol > 0 && tid < (WARM / 4)) {
        int wcol = startcol - WARM + tid * 4;
        vfloat4 v = *reinterpret_cast<const vfloat4*>(rin + wcol);
        // weight of last elem (k=3) is c^(508-4t); earlier elems get extra c's
        float s = v.w;
        s = fmaf(0.95f,     v.z, s);
        s = fmaf(0.9025f,   v.y, s);
        s = fmaf(0.857375f, v.x, s);
        wpart = exp2f((float)(WARM - 4 - 4 * tid) * LOG2C) * s;
    }
    #pragma unroll
    for (int d = 1; d < 64; d <<= 1)
        wpart += __shfl_xor(wpart, d, 64);

    // ---- main segment: 8 consecutive elements per thread (two float4) ----
    const int col    = startcol + tid * 8;
    const bool valid = (col < ROW_N);           // ROW_N % 8 == 0 -> all-or-nothing
    float e0=0.f,e1=0.f,e2=0.f,e3=0.f,e4=0.f,e5=0.f,e6=0.f,e7=0.f;
    if (valid) {
        vfloat4 va = *reinterpret_cast<const vfloat4*>(rin + col);
        vfloat4 vb = *reinterpret_cast<const vfloat4*>(rin + col + 4);
        e0=va.x; e1=va.y; e2=va.z; e3=va.w;
        e4=vb.x; e5=vb.y; e6=vb.z; e7=vb.w;
    }
    // local scan with zero initial state
    float l0 = e0;
    float l1 = fmaf(0.95f, l0, e1);
    float l2 = fmaf(0.95f, l1, e2);
    float l3 = fmaf(0.95f, l2, e3);
    float l4 = fmaf(0.95f, l3, e4);
    float l5 = fmaf(0.95f, l4, e5);
    float l6 = fmaf(0.95f, l5, e6);
    float l7 = fmaf(0.95f, l6, e7);

    // ---- wave64 inclusive scan of thread carries, hop d lanes = c^(8d) ----
    const float M0 = 0.66342043f;     // c^8
    const float M1 = 0.44012667f;     // c^16
    const float M2 = 0.19371148f;     // c^32
    const float M3 = 0.03752413f;     // c^64
    const float M4 = 0.00140806f;     // c^128
    const float M5 = 1.9826347e-06f;  // c^256
    float b = l7;
    { float t = __shfl_up(b, 1,  64); if (lane >= 1)  b = fmaf(M0, t, b); }
    { float t = __shfl_up(b, 2,  64); if (lane >= 2)  b = fmaf(M1, t, b); }
    { float t = __shfl_up(b, 4,  64); if (lane >= 4)  b = fmaf(M2, t, b); }
    { float t = __shfl_up(b, 8,  64); if (lane >= 8)  b = fmaf(M3, t, b); }
    { float t = __shfl_up(b, 16, 64); if (lane >= 16) b = fmaf(M4, t, b); }
    { float t = __shfl_up(b, 32, 64); if (lane >= 32) b = fmaf(M5, t, b); }

    float excl = __shfl_up(b, 1, 64);
    if (lane == 0) excl = 0.0f;

    if (lane == 63) warr[wave] = b;
    if (lane == 0)  wsum[wave] = wpart;
    __syncthreads();

    // ---- cross-wave fold (16 waves, hop multiplier c^512 ~ 3.9e-12) ----
    const float C512 = 3.930483e-12f;   // 0.95^512
    float E = 0.0f;
    for (int u = 0; u < wave; ++u) E = fmaf(E, C512, warr[u]);
    float carry_warm = 0.0f;
    #pragma unroll
    for (int u = 0; u < 16; ++u) carry_warm += wsum[u];

    // state at wave start, then at this thread's segment start
    float pw = exp2f((float)(512 * wave) * LOG2C);   // c^(512*wave) (underflow->0 ok)
    float Sw = fmaf(pw, carry_warm, E);
    float pl = exp2f((float)(8 * lane) * LOG2C);     // c^(8*lane)
    float Q  = fmaf(pl, Sw, excl);                   // state just before this segment

    if (valid) {
        vfloat4 ra, rb;
        ra.x = fmaf(0.95f,               Q, l0);
        ra.y = fmaf(0.9025f,             Q, l1);
        ra.z = fmaf(0.857375f,           Q, l2);
        ra.w = fmaf(0.81450625f,         Q, l3);
        rb.x = fmaf(0.7737809375f,       Q, l4);
        rb.y = fmaf(0.735091890625f,     Q, l5);
        rb.z = fmaf(0.69833729609375f,   Q, l6);
        rb.w = fmaf(0.6634204312890625f, Q, l7);
        __builtin_nontemporal_store(ra, reinterpret_cast<vfloat4*>(rout + col));
        __builtin_nontemporal_store(rb, reinterpret_cast<vfloat4*>(rout + col + 4));
    }
}

extern "C" void kernel_launch(void* const* d_in, const int* in_sizes, int n_in,
                              void* d_out, int out_size, void* d_ws, size_t ws_size,
                              hipStream_t stream) {
    const float* in = (const float*)d_in[0];
    float* out = (float*)d_out;
    dim3 grid(NTILES, NROWS);
    deemph_kernel<<<grid, 1024, 0, stream>>>(in, out);
}

// Round 4
// 46.007 us; speedup vs baseline: 1.1802x; 1.1802x over previous
//
#include <hip/hip_runtime.h>

// x[n] = 0.95 * x[n-1] + e[n], 64 rows x 480000 fp32, row-major.
// Single-pass block-local scan: each block handles a 4096-element tile of one
// row. Incoming state is approximated by a geometric-weighted reduction over
// the preceding 512 elements (0.95^512 ~ 4e-12 -> exact for fp32 purposes).
// 4 elements/thread so every global load/store instruction is a contiguous
// 1KB wave-span (full 64B lines; Round-3's 8/thread strided layout inflated
// WRITE_SIZE 11% via partial-line RMW). Nontemporal stores keep the streamed
// output out of L2/L3 so the input stays cache-resident.

#define ROW_N   480000
#define TILE    4096
#define WARM    512
#define NTILES  ((ROW_N + TILE - 1) / TILE)   // 118
#define NROWS   64

typedef float vfloat4 __attribute__((ext_vector_type(4)));  // clang-native for nontemporal builtin

__global__ __launch_bounds__(1024)
void deemph_kernel(const float* __restrict__ in, float* __restrict__ out) {
    const int row      = blockIdx.y;
    const int startcol = blockIdx.x * TILE;
    const int tid      = threadIdx.x;
    const int lane     = tid & 63;
    const int wave     = tid >> 6;

    const float* __restrict__ rin  = in  + (size_t)row * ROW_N;
    float*       __restrict__ rout = out + (size_t)row * ROW_N;

    __shared__ float warr[16];   // per-wave inclusive scan carries
    __shared__ float wsum[16];   // per-wave warm-up partial sums

    const float LOG2C = -0.07400058144377693f;  // log2(0.95)

    // ---- warm-up: carry_warm ~= x[startcol-1] = sum_j c^(511-j) e[start-512+j]
    // threads 0..127 each load one float4 of the 512-elem window (contiguous).
    float wpart = 0.0f;
    if (startcol > 0 && tid < (WARM / 4)) {
        int wcol = startcol - WARM + tid * 4;
        vfloat4 v = *reinterpret_cast<const vfloat4*>(rin + wcol);
        // elem j=4t+k has weight c^(511-4t-k); s = sum_k c^(3-k) v[k]
        float s = v.w;
        s = fmaf(0.95f,     v.z, s);
        s = fmaf(0.9025f,   v.y, s);
        s = fmaf(0.857375f, v.x, s);
        wpart = exp2f((float)(WARM - 4 - 4 * tid) * LOG2C) * s;   // c^(508-4t) * s
    }
    #pragma unroll
    for (int d = 1; d < 64; d <<= 1)
        wpart += __shfl_xor(wpart, d, 64);

    // ---- main segment: 4 consecutive elements per thread (one float4) ----
    const int col    = startcol + tid * 4;
    const bool valid = (col < ROW_N);          // ROW_N % 4 == 0 -> all-or-nothing
    float e0 = 0.f, e1 = 0.f, e2 = 0.f, e3 = 0.f;
    if (valid) {
        vfloat4 v = *reinterpret_cast<const vfloat4*>(rin + col);
        e0 = v.x; e1 = v.y; e2 = v.z; e3 = v.w;
    }
    // local scan with zero initial state
    float l0 = e0;
    float l1 = fmaf(0.95f, l0, e1);
    float l2 = fmaf(0.95f, l1, e2);
    float l3 = fmaf(0.95f, l2, e3);

    // ---- wave64 inclusive scan of thread carries, hop d lanes = c^(4d) ----
    const float M0 = 0.81450625f;     // c^4
    const float M1 = 0.66342043f;     // c^8
    const float M2 = 0.44012667f;     // c^16
    const float M3 = 0.19371148f;     // c^32
    const float M4 = 0.03752413f;     // c^64
    const float M5 = 0.00140806f;     // c^128
    float b = l3;
    { float t = __shfl_up(b, 1,  64); if (lane >= 1)  b = fmaf(M0, t, b); }
    { float t = __shfl_up(b, 2,  64); if (lane >= 2)  b = fmaf(M1, t, b); }
    { float t = __shfl_up(b, 4,  64); if (lane >= 4)  b = fmaf(M2, t, b); }
    { float t = __shfl_up(b, 8,  64); if (lane >= 8)  b = fmaf(M3, t, b); }
    { float t = __shfl_up(b, 16, 64); if (lane >= 16) b = fmaf(M4, t, b); }
    { float t = __shfl_up(b, 32, 64); if (lane >= 32) b = fmaf(M5, t, b); }

    float excl = __shfl_up(b, 1, 64);
    if (lane == 0) excl = 0.0f;

    if (lane == 63) warr[wave] = b;
    if (lane == 0)  wsum[wave] = wpart;
    __syncthreads();

    // ---- cross-wave fold (16 waves, hop multiplier c^256) ----
    const float C256 = 1.9826347e-06f;   // 0.95^256
    float E = 0.0f;
    for (int u = 0; u < wave; ++u) E = fmaf(E, C256, warr[u]);
    float carry_warm = 0.0f;
    #pragma unroll
    for (int u = 0; u < 16; ++u) carry_warm += wsum[u];

    // state at wave start, then at this thread's segment start
    float pw = exp2f((float)(256 * wave) * LOG2C);   // c^(256*wave)
    float Sw = fmaf(pw, carry_warm, E);
    float pl = exp2f((float)(4 * lane) * LOG2C);     // c^(4*lane)
    float Q  = fmaf(pl, Sw, excl);                   // state just before this segment

    if (valid) {
        vfloat4 r;
        r.x = fmaf(0.95f,       Q, l0);
        r.y = fmaf(0.9025f,     Q, l1);
        r.z = fmaf(0.857375f,   Q, l2);
        r.w = fmaf(0.81450625f, Q, l3);
        __builtin_nontemporal_store(r, reinterpret_cast<vfloat4*>(rout + col));
    }
}

extern "C" void kernel_launch(void* const* d_in, const int* in_sizes, int n_in,
                              void* d_out, int out_size, void* d_ws, size_t ws_size,
                              hipStream_t stream) {
    const float* in = (const float*)d_in[0];
    float* out = (float*)d_out;
    dim3 grid(NTILES, NROWS);
    deemph_kernel<<<grid, 1024, 0, stream>>>(in, out);
}

// Round 5
// 41.305 us; speedup vs baseline: 1.3146x; 1.1138x over previous
//
#include <hip/hip_runtime.h>

// x[n] = 0.95 * x[n-1] + e[n], 64 rows x 480000 fp32, row-major.
// Single-pass block-local scan, TILE=8192/block, 1024 threads.
// Each thread owns TWO 4-elem segments: [start+4t, +3] and [start+4096+4t, +3]
// -> every global load/store instruction is a contiguous full-wave 1KB span
// (full 64B lines), while per-thread MLP=3 independent loads issued up front.
// Incoming tile state approximated by geometric-weighted reduction over the
// preceding 512 elements (0.95^512 ~ 4e-12: exact for fp32). The hi half's
// warm-up term carries c^4096 -> underflows to 0, so it needs only the
// 32-entry wave-carry fold. One __syncthreads total.

#define ROW_N   480000
#define TILE    8192
#define HALF    4096
#define WARM    512
#define NTILES  ((ROW_N + TILE - 1) / TILE)   // 59
#define NROWS   64

typedef float vfloat4 __attribute__((ext_vector_type(4)));

__global__ __launch_bounds__(1024)
void deemph_kernel(const float* __restrict__ in, float* __restrict__ out) {
    const int row      = blockIdx.y;
    const int startcol = blockIdx.x * TILE;
    const int tid      = threadIdx.x;
    const int lane     = tid & 63;
    const int wave     = tid >> 6;

    const float* __restrict__ rin  = in  + (size_t)row * ROW_N;
    float*       __restrict__ rout = out + (size_t)row * ROW_N;

    __shared__ float warr[32];   // 32 virtual-wave carries (16 lo, 16 hi)
    __shared__ float wsum[16];   // per-wave warm-up partial sums

    const float LOG2C = -0.07400058144377693f;  // log2(0.95)

    // ---- issue all global loads up front (independent -> MLP) ----
    const int colL = startcol + tid * 4;            // lo half: always in range
    const int colH = startcol + HALF + tid * 4;     // hi half: may be past end
    const bool vH  = (colH < ROW_N);                // ROW_N % 4 == 0

    vfloat4 va = *reinterpret_cast<const vfloat4*>(rin + colL);
    vfloat4 vb = {0.f, 0.f, 0.f, 0.f};
    if (vH) vb = *reinterpret_cast<const vfloat4*>(rin + colH);
    vfloat4 vw = {0.f, 0.f, 0.f, 0.f};
    const bool doWarm = (startcol > 0) && (tid < (WARM / 4));
    if (doWarm) vw = *reinterpret_cast<const vfloat4*>(rin + (startcol - WARM + tid * 4));

    // ---- warm-up partial: elem j=4t+k weighted c^(511-4t-k) ----
    float wpart = 0.0f;
    if (doWarm) {
        float s = vw.w;
        s = fmaf(0.95f,     vw.z, s);
        s = fmaf(0.9025f,   vw.y, s);
        s = fmaf(0.857375f, vw.x, s);
        wpart = exp2f((float)(WARM - 4 - 4 * tid) * LOG2C) * s;   // c^(508-4t)*s
    }
    #pragma unroll
    for (int d = 1; d < 64; d <<= 1)
        wpart += __shfl_xor(wpart, d, 64);
    if (lane == 0) wsum[wave] = wpart;

    // ---- local scans (two independent chains -> ILP) ----
    float l0 = va.x;
    float l1 = fmaf(0.95f, l0, va.y);
    float l2 = fmaf(0.95f, l1, va.z);
    float l3 = fmaf(0.95f, l2, va.w);
    float h0 = vb.x;
    float h1 = fmaf(0.95f, h0, vb.y);
    float h2 = fmaf(0.95f, h1, vb.z);
    float h3 = fmaf(0.95f, h2, vb.w);

    // ---- wave64 inclusive scans of thread carries, hop d lanes = c^(4d) ----
    const float M0 = 0.81450625f;     // c^4
    const float M1 = 0.66342043f;     // c^8
    const float M2 = 0.44012667f;     // c^16
    const float M3 = 0.19371148f;     // c^32
    const float M4 = 0.03752413f;     // c^64
    const float M5 = 0.00140806f;     // c^128
    float bL = l3, bH = h3;
    { float t = __shfl_up(bL, 1,  64); float u = __shfl_up(bH, 1,  64); if (lane >= 1)  { bL = fmaf(M0, t, bL); bH = fmaf(M0, u, bH); } }
    { float t = __shfl_up(bL, 2,  64); float u = __shfl_up(bH, 2,  64); if (lane >= 2)  { bL = fmaf(M1, t, bL); bH = fmaf(M1, u, bH); } }
    { float t = __shfl_up(bL, 4,  64); float u = __shfl_up(bH, 4,  64); if (lane >= 4)  { bL = fmaf(M2, t, bL); bH = fmaf(M2, u, bH); } }
    { float t = __shfl_up(bL, 8,  64); float u = __shfl_up(bH, 8,  64); if (lane >= 8)  { bL = fmaf(M3, t, bL); bH = fmaf(M3, u, bH); } }
    { float t = __shfl_up(bL, 16, 64); float u = __shfl_up(bH, 16, 64); if (lane >= 16) { bL = fmaf(M4, t, bL); bH = fmaf(M4, u, bH); } }
    { float t = __shfl_up(bL, 32, 64); float u = __shfl_up(bH, 32, 64); if (lane >= 32) { bL = fmaf(M5, t, bL); bH = fmaf(M5, u, bH); } }

    float exL = __shfl_up(bL, 1, 64);
    float exH = __shfl_up(bH, 1, 64);
    if (lane == 0) { exL = 0.0f; exH = 0.0f; }

    if (lane == 63) { warr[wave] = bL; warr[16 + wave] = bH; }
    __syncthreads();

    // ---- cross-(virtual)wave fold, hop multiplier c^256 ----
    const float C256 = 1.9826347e-06f;   // 0.95^256
    float carry_warm = 0.0f;
    #pragma unroll
    for (int u = 0; u < 16; ++u) carry_warm += wsum[u];

    float E = 0.0f;
    for (int u = 0; u < wave; ++u) E = fmaf(E, C256, warr[u]);       // lo prefix
    float Eh = E;
    for (int u = wave; u < 16 + wave; ++u) Eh = fmaf(Eh, C256, warr[u]); // continue to hi

    float pw = exp2f((float)(256 * wave) * LOG2C);   // c^(256*wave)
    float SwL = fmaf(pw, carry_warm, E);             // state at lo wave start (+warm)
    // hi: warm term weight c^(256*(16+wave)) <= c^4096 -> 0; Eh alone is exact.
    float pl = exp2f((float)(4 * lane) * LOG2C);     // c^(4*lane)
    float QL = fmaf(pl, SwL, exL);                   // state before lo segment
    float QH = fmaf(pl, Eh,  exH);                   // state before hi segment

    {
        vfloat4 r;
        r.x = fmaf(0.95f,       QL, l0);
        r.y = fmaf(0.9025f,     QL, l1);
        r.z = fmaf(0.857375f,   QL, l2);
        r.w = fmaf(0.81450625f, QL, l3);
        __builtin_nontemporal_store(r, reinterpret_cast<vfloat4*>(rout + colL));
    }
    if (vH) {
        vfloat4 r;
        r.x = fmaf(0.95f,       QH, h0);
        r.y = fmaf(0.9025f,     QH, h1);
        r.z = fmaf(0.857375f,   QH, h2);
        r.w = fmaf(0.81450625f, QH, h3);
        __builtin_nontemporal_store(r, reinterpret_cast<vfloat4*>(rout + colH));
    }
}

extern "C" void kernel_launch(void* const* d_in, const int* in_sizes, int n_in,
                              void* d_out, int out_size, void* d_ws, size_t ws_size,
                              hipStream_t stream) {
    const float* in = (const float*)d_in[0];
    float* out = (float*)d_out;
    dim3 grid(NTILES, NROWS);
    deemph_kernel<<<grid, 1024, 0, stream>>>(in, out);
}